// Round 1
// 1725.657 us; speedup vs baseline: 1.1595x; 1.1595x over previous
//
#include <hip/hip_runtime.h>
#include <hip/hip_bf16.h>

typedef __bf16 bf16_t;
typedef __attribute__((ext_vector_type(8))) __bf16 bf16x8;
typedef __attribute__((ext_vector_type(4))) __bf16 bf16x4;
typedef __attribute__((ext_vector_type(4))) float f32x4;

#define NROWS 32768
#define FEAT  4096
#define INDIM 4097
#define HID   2048
#define PROJ  512
#define NPAD  33024   /* 129 tiles * 256 (also 258 * 128) */
#define MT256 129
#define SENT  0xFFFFFFFFu

// ---------------------------------------------------------------- utilities
__device__ __forceinline__ void load_lds16(const bf16_t* g, char* s) {
  // async global->LDS, 16B/lane. LDS dest is wave-uniform base + lane*16.
  __builtin_amdgcn_global_load_lds(
      (__attribute__((address_space(1))) void*)(void*)g,
      (__attribute__((address_space(3))) void*)s, 16, 0, 0);
}

// ---------------------------------------------------------------- prep
__global__ __launch_bounds__(256) void init_kernel(unsigned* __restrict__ perm,
                                                   int* __restrict__ cnt) {
  int i = blockIdx.x * 256 + threadIdx.x;
  if (i < NPAD) perm[i] = SENT;
  if (i < 4) cnt[i] = 0;
}

__global__ __launch_bounds__(256) void count_kernel(const float* __restrict__ x,
                                                    int* __restrict__ cnt) {
  int i = blockIdx.x * 256 + threadIdx.x;
  if (i >= NROWS) return;
  float f = x[(long)i * INDIM + FEAT];
  if (f > 0.5f) atomicAdd(&cnt[0], 1);
}

// groups padded to 256 now (256-row GEMM tiles must not straddle nat/oth).
// worst case: pad_nat + pad_oth = 256 exactly -> total <= 33024 = NPAD.
__global__ __launch_bounds__(256) void scatter_kernel(const float* __restrict__ x,
                                                      unsigned* __restrict__ perm,
                                                      int* __restrict__ cnt) {
  int i = blockIdx.x * 256 + threadIdx.x;
  if (i >= NROWS) return;
  float f = x[(long)i * INDIM + FEAT];
  int g = (f > 0.5f) ? 0 : 1;                 // 0 = nat, 1 = oth
  int pos = atomicAdd(&cnt[1 + g], 1);
  int off_oth = ((cnt[0] + 255) >> 8) << 8;   // cnt[0] final (prev kernel)
  int q = (g == 0) ? pos : off_oth + pos;
  perm[q] = (unsigned)i;
}

// x (fp32, pitch 4097, drop flag col) -> xbf (bf16, pitch 4096)
__global__ __launch_bounds__(256) void convert_x_kernel(const float* __restrict__ x,
                                                        bf16_t* __restrict__ xbf) {
  const int lane = threadIdx.x & 63;
  const long wid = ((long)blockIdx.x * 256 + threadIdx.x) >> 6;
  const long chunk = wid * 512;
  const long row = chunk >> 12;          // /4096
  const long col = chunk & 4095;
  const float* src = x + row * INDIM + col + lane;
  bf16_t* dst = xbf + chunk + lane;
#pragma unroll
  for (int j = 0; j < 8; ++j)
    dst[j * 64] = (bf16_t)src[j * 64];
}

// W[K][N] fp32 -> Wt[N][K] bf16, 32x32 LDS tiles
__global__ __launch_bounds__(256) void transpose_convert_kernel(
    const float* __restrict__ W, bf16_t* __restrict__ Wt, int K, int N) {
  __shared__ float tile[32][33];
  const int n0 = blockIdx.x << 5;
  const int k0 = blockIdx.y << 5;
  const int t = threadIdx.x;
  const int r = t >> 3;
  const int c4 = (t & 7) << 2;
  f32x4 v = *(const f32x4*)(W + (long)(k0 + r) * N + n0 + c4);
#pragma unroll
  for (int i = 0; i < 4; ++i) tile[r][c4 + i] = v[i];
  __syncthreads();
  bf16x4 o;
#pragma unroll
  for (int i = 0; i < 4; ++i) o[i] = (bf16_t)tile[c4 + i][r];
  *(bf16x4*)(Wt + (long)(n0 + r) * K + k0 + c4) = o;
}

// ---------------------------------------------------------------- GEMM 256^2 8-phase
// C[M][N] = A[M][K] @ Bt[N][K]^T (+bias). 256x256 tile, BK=64, 512 thr = 8 waves
// (2M x 4N), per-wave 128x64 out, 16x16x32 bf16 MFMA. Double-buffered 128KB LDS,
// half-tile (128 rows x 64 k) staging via global_load_lds, XOR-swizzled
// (pre-swizzled global source + swizzled ds_read -> conflict-free), counted
// vmcnt(6) at phases 4/8 only, raw s_barrier pairs, setprio around MFMA.
//
// LDS map (bytes): A: buf*32768 + h*16384 + j*8192 + wave*1024 (+lane*16)
//                  B: 65536 + same.   Row = 128B (64 bf16).
// Swizzle: LDS chunk p of row r holds global k-chunk (p ^ (r&7)); reader at
// (row rr, chunk cr) reads LDS chunk cr ^ (rr&7).  rr&7 == l16&7 on all reads.
template <bool GATHER, bool RELU_BF16>
__global__ __launch_bounds__(512, 2) void gemm256_kernel(
    const bf16_t* __restrict__ A,
    const bf16_t* __restrict__ BtNat, const bf16_t* __restrict__ BtOth,
    const float* __restrict__ biasNat, const float* __restrict__ biasOth,
    void* __restrict__ Cout,
    const unsigned* __restrict__ perm, const int* __restrict__ cnt,
    const int K, const int N, const int ntn) {
  extern __shared__ char smem[];
  const int tid = threadIdx.x;

  // T1: XCD-aware bijective block swizzle (m204 variant)
  const int nwg = gridDim.x;
  const int q8 = nwg >> 3, r8g = nwg & 7;
  const int xcd = blockIdx.x & 7, lo = blockIdx.x >> 3;
  const int wg = (xcd < r8g ? xcd * (q8 + 1) : r8g * (q8 + 1) + (xcd - r8g) * q8) + lo;
  const int tile_m = wg / ntn;
  const int tile_n = wg - tile_m * ntn;
  const int qbase = tile_m << 8;
  if (perm[qbase] == SENT) return;      // dead tile (uniform per block)
  const int n0 = tile_n << 8;

  const int off_oth = ((cnt[0] + 255) >> 8) << 8;
  const bool nat = qbase < off_oth;
  const bf16_t* __restrict__ Bt = nat ? BtNat : BtOth;
  const float* __restrict__ bias = nat ? biasNat : biasOth;

  const int nkt = K >> 6;     // 64-wide K tiles
  const int niter = K >> 7;   // 2 K-tiles per iteration

  // ---- staging source pointers (per-thread). chunk c=j*512+tid; rr=c>>3; p=c&7.
  // A half h: global row = qbase + j*128 + h*64 + (tid>>3)
  // B half h: global nrow = n0 + j*128 + (tid>>8)*64 + h*32 + ((tid>>3)&31)
  const int r8 = tid >> 3;                       // 0..63
  const int kco = ((tid & 7) ^ (r8 & 7)) << 3;   // pre-swizzled k-chunk (elems)
  long r00, r01, r10, r11;                       // aS<h><j>
  if (GATHER) {
    unsigned p00 = perm[qbase + r8];
    unsigned p10 = perm[qbase + 64 + r8];
    unsigned p01 = perm[qbase + 128 + r8];
    unsigned p11 = perm[qbase + 192 + r8];
    r00 = (p00 == SENT) ? 0 : (long)p00;   // pad rows read row 0 (harmless)
    r10 = (p10 == SENT) ? 0 : (long)p10;
    r01 = (p01 == SENT) ? 0 : (long)p01;
    r11 = (p11 == SENT) ? 0 : (long)p11;
  } else {
    r00 = qbase + r8;       r10 = qbase + 64 + r8;
    r01 = qbase + 128 + r8; r11 = qbase + 192 + r8;
  }
  const bf16_t* aS00 = A + r00 * K + kco;
  const bf16_t* aS10 = A + r10 * K + kco;
  const bf16_t* aS01 = A + r01 * K + kco;
  const bf16_t* aS11 = A + r11 * K + kco;

  const int b0 = tid >> 8;       // 0/1
  const int r32 = r8 & 31;
  const bf16_t* bS00 = Bt + (long)(n0 + b0 * 64 + r32) * K + kco;
  const bf16_t* bS10 = Bt + (long)(n0 + b0 * 64 + 32 + r32) * K + kco;
  const bf16_t* bS01 = Bt + (long)(n0 + 128 + b0 * 64 + r32) * K + kco;
  const bf16_t* bS11 = Bt + (long)(n0 + 128 + b0 * 64 + 32 + r32) * K + kco;

  // ---- reader lane geometry
  const int wave = tid >> 6, lane = tid & 63;
  const int wmi = wave >> 2, wni = wave & 3;
  const int quad = lane >> 4, l16 = lane & 15;
  const int x7 = l16 & 7;
  const int rx0 = (quad ^ x7) << 4;
  const int rx1 = ((quad + 4) ^ x7) << 4;
  const int aRB = (wmi * 64 + l16) * 128;
  const int bRB = (wni * 32 + l16) * 128;
  const int wbase = wave << 10;

#define ADST(buf, h, j) ((buf) * 32768 + (h) * 16384 + (j) * 8192)
#define BDST(buf, h, j) (65536 + (buf) * 32768 + (h) * 16384 + (j) * 8192)
#define STG_A(buf, h, kt) do { const long ko = ((kt) < nkt) ? ((long)(kt) << 6) : 0; \
    load_lds16(aS##h##0 + ko, smem + ADST(buf, h, 0) + wbase); \
    load_lds16(aS##h##1 + ko, smem + ADST(buf, h, 1) + wbase); } while (0)
#define STG_B(buf, h, kt) do { const long ko = ((kt) < nkt) ? ((long)(kt) << 6) : 0; \
    load_lds16(bS##h##0 + ko, smem + BDST(buf, h, 0) + wbase); \
    load_lds16(bS##h##1 + ko, smem + BDST(buf, h, 1) + wbase); } while (0)
#define RD_A(buf, mi, ks) af[(mi) & 3][ks] = *(const bf16x8*)(smem + (buf) * 32768 \
    + ((mi) >> 2) * 16384 + aRB + ((mi) & 3) * 2048 + rx##ks)
#define RD_B(buf, nf, ks) bfr[nf][ks] = *(const bf16x8*)(smem + 65536 + (buf) * 32768 \
    + ((nf) >> 1) * 16384 + bRB + ((nf) & 1) * 2048 + rx##ks)
#define MFMA_PH(m0_, n0_) do { \
    __builtin_amdgcn_s_setprio(1); \
    _Pragma("unroll") for (int ks_ = 0; ks_ < 2; ++ks_) \
    _Pragma("unroll") for (int mi_ = 0; mi_ < 4; ++mi_) \
    _Pragma("unroll") for (int ni_ = 0; ni_ < 2; ++ni_) \
      acc[(m0_) + mi_][(n0_) + ni_] = __builtin_amdgcn_mfma_f32_16x16x32_bf16( \
          af[mi_][ks_], bfr[(n0_) + ni_][ks_], acc[(m0_) + mi_][(n0_) + ni_], 0, 0, 0); \
    __builtin_amdgcn_s_setprio(0); } while (0)
#define SBAR do { __builtin_amdgcn_sched_barrier(0); __builtin_amdgcn_s_barrier(); } while (0)
#define VMC6 asm volatile("s_waitcnt vmcnt(6)" ::: "memory")

  f32x4 acc[8][4] = {};
  bf16x8 af[4][2], bfr[4][2];

  // prologue: tile0 {A0,B0,B1,A1}, tile1 {A0,B0,B1}; A1(tile1) staged in ph1.
  STG_A(0, 0, 0); STG_B(0, 0, 0); STG_B(0, 1, 0); STG_A(0, 1, 0);
  STG_A(1, 0, 1); STG_B(1, 0, 1); STG_B(1, 1, 1);
  VMC6; SBAR;

  for (int t = 0; t < niter; ++t) {
    const int c = t << 1;
    // ph1: quadrant m0-3 x n0-1 of tile c (buf0); stage A1(c+1)->buf1
    RD_A(0, 0, 0); RD_A(0, 0, 1); RD_A(0, 1, 0); RD_A(0, 1, 1);
    RD_A(0, 2, 0); RD_A(0, 2, 1); RD_A(0, 3, 0); RD_A(0, 3, 1);
    RD_B(0, 0, 0); RD_B(0, 0, 1); RD_B(0, 1, 0); RD_B(0, 1, 1);
    STG_A(1, 1, c + 1);
    SBAR;
    MFMA_PH(0, 0);
    SBAR;
    // ph2: m0-3 x n2-3; stage A0(c+2)->buf0 (region's last read was ph1)
    RD_B(0, 2, 0); RD_B(0, 2, 1); RD_B(0, 3, 0); RD_B(0, 3, 1);
    STG_A(0, 0, c + 2);
    SBAR;
    MFMA_PH(0, 2);
    SBAR;
    // ph3: m4-7 x n0-1 (bfr[0..1] still live from ph1); stage B0(c+2)
    RD_A(0, 4, 0); RD_A(0, 4, 1); RD_A(0, 5, 0); RD_A(0, 5, 1);
    RD_A(0, 6, 0); RD_A(0, 6, 1); RD_A(0, 7, 0); RD_A(0, 7, 1);
    STG_B(0, 0, c + 2);
    SBAR;
    MFMA_PH(4, 0);
    SBAR;
    // ph4: m4-7 x n2-3; stage B1(c+2); counted drain for next K-tile's reads
    STG_B(0, 1, c + 2);
    SBAR;
    MFMA_PH(4, 2);
    VMC6;
    SBAR;
    // ph5-8: tile c+1 (buf1); stages A1(c+2), then tile c+3 -> buf1
    RD_A(1, 0, 0); RD_A(1, 0, 1); RD_A(1, 1, 0); RD_A(1, 1, 1);
    RD_A(1, 2, 0); RD_A(1, 2, 1); RD_A(1, 3, 0); RD_A(1, 3, 1);
    RD_B(1, 0, 0); RD_B(1, 0, 1); RD_B(1, 1, 0); RD_B(1, 1, 1);
    STG_A(0, 1, c + 2);
    SBAR;
    MFMA_PH(0, 0);
    SBAR;
    // ph6
    RD_B(1, 2, 0); RD_B(1, 2, 1); RD_B(1, 3, 0); RD_B(1, 3, 1);
    STG_A(1, 0, c + 3);
    SBAR;
    MFMA_PH(0, 2);
    SBAR;
    // ph7
    RD_A(1, 4, 0); RD_A(1, 4, 1); RD_A(1, 5, 0); RD_A(1, 5, 1);
    RD_A(1, 6, 0); RD_A(1, 6, 1); RD_A(1, 7, 0); RD_A(1, 7, 1);
    STG_B(1, 0, c + 3);
    SBAR;
    MFMA_PH(4, 0);
    SBAR;
    // ph8
    STG_B(1, 1, c + 3);
    SBAR;
    MFMA_PH(4, 2);
    VMC6;
    SBAR;
  }

  // drain pending LDS-DMA before teardown/stores
  asm volatile("s_waitcnt vmcnt(0)" ::: "memory");

  float bv[4];
#pragma unroll
  for (int nf = 0; nf < 4; ++nf) bv[nf] = bias[n0 + wni * 64 + nf * 16 + l16];

  // C/D layout: col = lane&15, row = quad*4 + reg (m89-verified)
#pragma unroll
  for (int mi = 0; mi < 8; ++mi) {
    const long row0 = (long)(qbase + wmi * 128 + mi * 16 + quad * 4);
#pragma unroll
    for (int nf = 0; nf < 4; ++nf) {
      const int col = n0 + wni * 64 + nf * 16 + l16;
#pragma unroll
      for (int r = 0; r < 4; ++r) {
        float v = acc[mi][nf][r] + bv[nf];
        if (RELU_BF16) {
          v = fmaxf(v, 0.0f);
          ((bf16_t*)Cout)[(row0 + r) * N + col] = (bf16_t)v;
        } else {
          ((float*)Cout)[(row0 + r) * N + col] = v;
        }
      }
    }
  }
#undef ADST
#undef BDST
#undef STG_A
#undef STG_B
#undef RD_A
#undef RD_B
#undef MFMA_PH
#undef SBAR
#undef VMC6
}

// ---------------------------------------------------------------- epilogue
__global__ __launch_bounds__(256) void epilogue_kernel(
    const float* __restrict__ z,                       // [NPAD][512]
    const float* __restrict__ Wc0, const float* __restrict__ bc0,
    const float* __restrict__ Wc1, const float* __restrict__ bc1,
    const unsigned* __restrict__ perm, const int* __restrict__ cnt,
    float* __restrict__ out_z, float* __restrict__ out_logits) {
  __shared__ float WcL[2][PROJ * 3];
  for (int i = threadIdx.x; i < PROJ * 3; i += 256) {
    WcL[0][i] = Wc0[i];
    WcL[1][i] = Wc1[i];
  }
  __syncthreads();
  const int wave = threadIdx.x >> 6;
  const int lane = threadIdx.x & 63;
  const int q = blockIdx.x * 4 + wave;
  const unsigned orig = perm[q];
  if (orig == SENT) return;             // pad row
  const int n_nat = cnt[0];
  const int off_oth = ((n_nat + 255) >> 8) << 8;
  const int g = (q < off_oth) ? 0 : 1;

  float zv[8];
  float ss = 0.f, l0 = 0.f, l1 = 0.f, l2 = 0.f;
#pragma unroll
  for (int i = 0; i < 8; ++i) {
    const int k = i * 64 + lane;
    float v = z[(long)q * PROJ + k];
    zv[i] = v;
    ss += v * v;
    float r = fmaxf(v, 0.f);
    const float* w = &WcL[g][k * 3];
    l0 += r * w[0];
    l1 += r * w[1];
    l2 += r * w[2];
  }
#pragma unroll
  for (int off = 32; off > 0; off >>= 1) {
    ss += __shfl_xor(ss, off);
    l0 += __shfl_xor(l0, off);
    l1 += __shfl_xor(l1, off);
    l2 += __shfl_xor(l2, off);
  }
  const float inv = 1.f / fmaxf(sqrtf(ss), 1e-12f);
#pragma unroll
  for (int i = 0; i < 8; ++i)
    out_z[(long)orig * PROJ + i * 64 + lane] = zv[i] * inv;
  if (lane == 0) {
    const float* bc = g ? bc1 : bc0;
    out_logits[(long)orig * 3 + 0] = l0 + bc[0];
    out_logits[(long)orig * 3 + 1] = l1 + bc[1];
    out_logits[(long)orig * 3 + 2] = l2 + bc[2];
  }
}

// ---------------------------------------------------------------- launch
extern "C" void kernel_launch(void* const* d_in, const int* in_sizes, int n_in,
                              void* d_out, int out_size, void* d_ws, size_t ws_size,
                              hipStream_t stream) {
  const float* x   = (const float*)d_in[0];
  const float* W1n = (const float*)d_in[1];
  const float* b1n = (const float*)d_in[2];
  const float* W2n = (const float*)d_in[3];
  const float* b2n = (const float*)d_in[4];
  const float* Wcn = (const float*)d_in[5];
  const float* bcn = (const float*)d_in[6];
  const float* W1o = (const float*)d_in[7];
  const float* b1o = (const float*)d_in[8];
  const float* W2o = (const float*)d_in[9];
  const float* b2o = (const float*)d_in[10];
  const float* Wco = (const float*)d_in[11];
  const float* bco = (const float*)d_in[12];

  char* ws = (char*)d_ws;
  bf16_t* xbf  = (bf16_t*)ws;                                   // 268,435,456
  float*  z_ws = (float*)ws;                                    // alias (xbf dead after GEMM1)
  size_t off = 268435456;
  bf16_t* W1tn = (bf16_t*)(ws + off); off += (size_t)FEAT * HID * 2;
  bf16_t* W1to = (bf16_t*)(ws + off); off += (size_t)FEAT * HID * 2;
  bf16_t* W2tn = (bf16_t*)(ws + off); off += (size_t)HID * PROJ * 2;
  bf16_t* W2to = (bf16_t*)(ws + off); off += (size_t)HID * PROJ * 2;
  bf16_t* h_ws = (bf16_t*)(ws + off); off += (size_t)NPAD * HID * 2;
  unsigned* perm = (unsigned*)(ws + off); off += (size_t)NPAD * 4;
  int* cnt = (int*)(ws + off);

  float* out_z = (float*)d_out;
  float* out_logits = out_z + (size_t)NROWS * PROJ;

  static bool attr_done = false;
  if (!attr_done) {
    auto* k1 = gemm256_kernel<true, true>;
    auto* k2 = gemm256_kernel<false, false>;
    (void)hipFuncSetAttribute(reinterpret_cast<const void*>(k1),
                              hipFuncAttributeMaxDynamicSharedMemorySize, 131072);
    (void)hipFuncSetAttribute(reinterpret_cast<const void*>(k2),
                              hipFuncAttributeMaxDynamicSharedMemorySize, 131072);
    attr_done = true;
  }

  // 1) partition rows by flag (padded to 256, sentinel-filled perm)
  init_kernel<<<(NPAD + 255) / 256, 256, 0, stream>>>(perm, cnt);
  count_kernel<<<NROWS / 256, 256, 0, stream>>>(x, cnt);
  scatter_kernel<<<NROWS / 256, 256, 0, stream>>>(x, perm, cnt);

  // 2) dtype conversions
  convert_x_kernel<<<(int)(((long)NROWS * FEAT / 512) / 4), 256, 0, stream>>>(x, xbf);
  transpose_convert_kernel<<<dim3(HID / 32, FEAT / 32), 256, 0, stream>>>(W1n, W1tn, FEAT, HID);
  transpose_convert_kernel<<<dim3(HID / 32, FEAT / 32), 256, 0, stream>>>(W1o, W1to, FEAT, HID);
  transpose_convert_kernel<<<dim3(PROJ / 32, HID / 32), 256, 0, stream>>>(W2n, W2tn, HID, PROJ);
  transpose_convert_kernel<<<dim3(PROJ / 32, HID / 32), 256, 0, stream>>>(W2o, W2to, HID, PROJ);

  // 3) h = relu(feat @ W1 + b1)  (gathered A rows, bf16 out)
  gemm256_kernel<true, true><<<dim3(MT256 * 8), 512, 131072, stream>>>(
      xbf, W1tn, W1to, b1n, b1o, (void*)h_ws, perm, cnt, FEAT, HID, 8);

  // 4) z = h @ W2 + b2  (fp32 out, overwrites dead xbf region)
  gemm256_kernel<false, false><<<dim3(MT256 * 2), 512, 131072, stream>>>(
      h_ws, W2tn, W2to, b2n, b2o, (void*)z_ws, perm, cnt, HID, PROJ, 2);

  // 5) normalize + classifier, scatter to original row order
  epilogue_kernel<<<NPAD / 4, 256, 0, stream>>>(
      z_ws, Wcn, bcn, Wco, bco, perm, cnt, out_z, out_logits);
}

// Round 2
// 1695.939 us; speedup vs baseline: 1.1798x; 1.0175x over previous
//
#include <hip/hip_runtime.h>
#include <hip/hip_bf16.h>

typedef __bf16 bf16_t;
typedef __attribute__((ext_vector_type(8))) __bf16 bf16x8;
typedef __attribute__((ext_vector_type(4))) __bf16 bf16x4;
typedef __attribute__((ext_vector_type(4))) float f32x4;

#define NROWS 32768
#define FEAT  4096
#define INDIM 4097
#define HID   2048
#define PROJ  512
#define NPAD  33024   /* 129 tiles * 256 */
#define MT256 129
#define SENT  0xFFFFFFFFu

// ---------------------------------------------------------------- utilities
__device__ __forceinline__ void load_lds16(const bf16_t* g, char* s) {
  // async global->LDS, 16B/lane. LDS dest is wave-uniform base + lane*16.
  __builtin_amdgcn_global_load_lds(
      (__attribute__((address_space(1))) void*)(void*)g,
      (__attribute__((address_space(3))) void*)s, 16, 0, 0);
}

// ---------------------------------------------------------------- prep
__global__ __launch_bounds__(256) void init_kernel(unsigned* __restrict__ perm,
                                                   int* __restrict__ cnt) {
  int i = blockIdx.x * 256 + threadIdx.x;
  if (i < NPAD) perm[i] = SENT;
  if (i < 4) cnt[i] = 0;
}

__global__ __launch_bounds__(256) void count_kernel(const float* __restrict__ x,
                                                    int* __restrict__ cnt) {
  int i = blockIdx.x * 256 + threadIdx.x;
  if (i >= NROWS) return;
  float f = x[(long)i * INDIM + FEAT];
  if (f > 0.5f) atomicAdd(&cnt[0], 1);
}

// groups padded to 256 (tiles must not straddle nat/oth); worst-case pad sum
// is exactly 256 -> total <= 33024 = NPAD.
__global__ __launch_bounds__(256) void scatter_kernel(const float* __restrict__ x,
                                                      unsigned* __restrict__ perm,
                                                      int* __restrict__ cnt) {
  int i = blockIdx.x * 256 + threadIdx.x;
  if (i >= NROWS) return;
  float f = x[(long)i * INDIM + FEAT];
  int g = (f > 0.5f) ? 0 : 1;                 // 0 = nat, 1 = oth
  int pos = atomicAdd(&cnt[1 + g], 1);
  int off_oth = ((cnt[0] + 255) >> 8) << 8;   // cnt[0] final (prev kernel)
  int q = (g == 0) ? pos : off_oth + pos;
  perm[q] = (unsigned)i;
}

// x (fp32, pitch 4097, drop flag col) -> xbf (bf16, pitch 4096)
// lane-contiguous 8 elems -> one 16B bf16x8 store; scalar 4B loads (row base
// only 4B-aligned), L1 absorbs the per-instr stride-32B pattern.
__global__ __launch_bounds__(256) void convert_x_kernel(const float* __restrict__ x,
                                                        bf16_t* __restrict__ xbf) {
  const long total = (long)NROWS * FEAT / 8;     // 16,777,216 8-elem units
  const long stride = (long)gridDim.x * 256;
  for (long u = (long)blockIdx.x * 256 + threadIdx.x; u < total; u += stride) {
    const long e = u << 3;
    const long row = e >> 12;          // /4096
    const long col = e & 4095;
    const float* s = x + row * INDIM + col;
    bf16x8 o;
#pragma unroll
    for (int j = 0; j < 8; ++j) o[j] = (bf16_t)s[j];
    *(bf16x8*)(xbf + e) = o;
  }
}

// W[K][N] fp32 -> Wt[N][K] bf16, 32x32 LDS tiles
__global__ __launch_bounds__(256) void transpose_convert_kernel(
    const float* __restrict__ W, bf16_t* __restrict__ Wt, int K, int N) {
  __shared__ float tile[32][33];
  const int n0 = blockIdx.x << 5;
  const int k0 = blockIdx.y << 5;
  const int t = threadIdx.x;
  const int r = t >> 3;
  const int c4 = (t & 7) << 2;
  f32x4 v = *(const f32x4*)(W + (long)(k0 + r) * N + n0 + c4);
#pragma unroll
  for (int i = 0; i < 4; ++i) tile[r][c4 + i] = v[i];
  __syncthreads();
  bf16x4 o;
#pragma unroll
  for (int i = 0; i < 4; ++i) o[i] = (bf16_t)tile[c4 + i][r];
  *(bf16x4*)(Wt + (long)(n0 + r) * K + k0 + c4) = o;
}

// ---------------------------------------------------------------- GEMM 256^2 8-phase
// C[M][N] = A[M][K] @ Bt[N][K]^T (+bias). 256x256 tile, BK=64, 512 thr = 8 waves
// (2M x 4N), per-wave 128x64 out, 16x16x32 bf16 MFMA. Double-buffered 128KB LDS,
// XOR-swizzled staging via global_load_lds (pre-swizzled global source +
// swizzled ds_read), SINGLE barrier per phase (waves may stagger within a
// phase: one wave's MFMA covers another's ds_read latency), counted vmcnt(8)
// at phases 4/8 only, setprio around MFMA.
//
// Stage schedule (min issue->drain distance = 4 phases):
//   ph1: -            ph5: -
//   ph2: A0,B0(c+2)   ph6: A0,B0(c+3)
//   ph3: B1(c+2)      ph7: B1(c+3)
//   ph4: A1(c+2) VMC8 ph8: A1(c+3) VMC8
// Region-free proof: buf reads per phase touch A-h0,B-h0 (ph1/5), B-h1 (ph2/6),
// A-h1 (ph3/7); each STG lands >= 1 barrier after its region's last read.
// vmcnt(8) at ph4 drains prev-iter's buf1 groups (8 loads); at ph8 drains
// this-iter's buf0 groups.
template <bool GATHER, bool RELU_BF16>
__global__ __launch_bounds__(512, 2) void gemm256_kernel(
    const bf16_t* __restrict__ A,
    const bf16_t* __restrict__ BtNat, const bf16_t* __restrict__ BtOth,
    const float* __restrict__ biasNat, const float* __restrict__ biasOth,
    void* __restrict__ Cout,
    const unsigned* __restrict__ perm, const int* __restrict__ cnt,
    const int K, const int N, const int ntn) {
  extern __shared__ char smem[];
  const int tid = threadIdx.x;

  // T1: XCD-aware bijective block swizzle (m204 variant)
  const int nwg = gridDim.x;
  const int q8 = nwg >> 3, r8g = nwg & 7;
  const int xcd = blockIdx.x & 7, lo = blockIdx.x >> 3;
  const int wg = (xcd < r8g ? xcd * (q8 + 1) : r8g * (q8 + 1) + (xcd - r8g) * q8) + lo;
  const int tile_m = wg / ntn;
  const int tile_n = wg - tile_m * ntn;
  const int qbase = tile_m << 8;
  if (perm[qbase] == SENT) return;      // dead tile (uniform per block)
  const int n0 = tile_n << 8;

  const int off_oth = ((cnt[0] + 255) >> 8) << 8;
  const bool nat = qbase < off_oth;
  const bf16_t* __restrict__ Bt = nat ? BtNat : BtOth;
  const float* __restrict__ bias = nat ? biasNat : biasOth;

  const int nkt = K >> 6;     // 64-wide K tiles
  const int niter = K >> 7;   // 2 K-tiles per iteration

  // ---- staging source pointers. chunk c=j*512+tid; rr=c>>3; p=c&7.
  const int r8 = tid >> 3;                       // 0..63
  const int kco = ((tid & 7) ^ (r8 & 7)) << 3;   // pre-swizzled k-chunk (elems)
  long r00, r01, r10, r11;
  if (GATHER) {
    unsigned p00 = perm[qbase + r8];
    unsigned p10 = perm[qbase + 64 + r8];
    unsigned p01 = perm[qbase + 128 + r8];
    unsigned p11 = perm[qbase + 192 + r8];
    r00 = (p00 == SENT) ? 0 : (long)p00;   // pad rows read row 0 (harmless)
    r10 = (p10 == SENT) ? 0 : (long)p10;
    r01 = (p01 == SENT) ? 0 : (long)p01;
    r11 = (p11 == SENT) ? 0 : (long)p11;
  } else {
    r00 = qbase + r8;       r10 = qbase + 64 + r8;
    r01 = qbase + 128 + r8; r11 = qbase + 192 + r8;
  }
  const bf16_t* aS00 = A + r00 * K + kco;
  const bf16_t* aS10 = A + r10 * K + kco;
  const bf16_t* aS01 = A + r01 * K + kco;
  const bf16_t* aS11 = A + r11 * K + kco;

  const int b0 = tid >> 8;       // 0/1
  const int r32 = r8 & 31;
  const bf16_t* bS00 = Bt + (long)(n0 + b0 * 64 + r32) * K + kco;
  const bf16_t* bS10 = Bt + (long)(n0 + b0 * 64 + 32 + r32) * K + kco;
  const bf16_t* bS01 = Bt + (long)(n0 + 128 + b0 * 64 + r32) * K + kco;
  const bf16_t* bS11 = Bt + (long)(n0 + 128 + b0 * 64 + 32 + r32) * K + kco;

  // ---- reader lane geometry
  const int wave = tid >> 6, lane = tid & 63;
  const int wmi = wave >> 2, wni = wave & 3;
  const int quad = lane >> 4, l16 = lane & 15;
  const int x7 = l16 & 7;
  const int rx0 = (quad ^ x7) << 4;
  const int rx1 = ((quad + 4) ^ x7) << 4;
  const int aRB = (wmi * 64 + l16) * 128;
  const int bRB = (wni * 32 + l16) * 128;
  const int wbase = wave << 10;

#define ADST(buf, h, j) ((buf) * 32768 + (h) * 16384 + (j) * 8192)
#define BDST(buf, h, j) (65536 + (buf) * 32768 + (h) * 16384 + (j) * 8192)
#define STG_A(buf, h, kt) do { const long ko = ((kt) < nkt) ? ((long)(kt) << 6) : 0; \
    load_lds16(aS##h##0 + ko, smem + ADST(buf, h, 0) + wbase); \
    load_lds16(aS##h##1 + ko, smem + ADST(buf, h, 1) + wbase); } while (0)
#define STG_B(buf, h, kt) do { const long ko = ((kt) < nkt) ? ((long)(kt) << 6) : 0; \
    load_lds16(bS##h##0 + ko, smem + BDST(buf, h, 0) + wbase); \
    load_lds16(bS##h##1 + ko, smem + BDST(buf, h, 1) + wbase); } while (0)
#define RD_A(buf, mi, ks) af[(mi) & 3][ks] = *(const bf16x8*)(smem + (buf) * 32768 \
    + ((mi) >> 2) * 16384 + aRB + ((mi) & 3) * 2048 + rx##ks)
#define RD_B(buf, nf, ks) bfr[nf][ks] = *(const bf16x8*)(smem + 65536 + (buf) * 32768 \
    + ((nf) >> 1) * 16384 + bRB + ((nf) & 1) * 2048 + rx##ks)
#define MFMA_PH(m0_, n0_) do { \
    __builtin_amdgcn_s_setprio(1); \
    _Pragma("unroll") for (int ks_ = 0; ks_ < 2; ++ks_) \
    _Pragma("unroll") for (int mi_ = 0; mi_ < 4; ++mi_) \
    _Pragma("unroll") for (int ni_ = 0; ni_ < 2; ++ni_) \
      acc[(m0_) + mi_][(n0_) + ni_] = __builtin_amdgcn_mfma_f32_16x16x32_bf16( \
          af[mi_][ks_], bfr[(n0_) + ni_][ks_], acc[(m0_) + mi_][(n0_) + ni_], 0, 0, 0); \
    __builtin_amdgcn_s_setprio(0); } while (0)
#define SCHED0 __builtin_amdgcn_sched_barrier(0)
#define SBAR do { __builtin_amdgcn_sched_barrier(0); __builtin_amdgcn_s_barrier(); } while (0)
#define VMC8 asm volatile("s_waitcnt vmcnt(8)" ::: "memory")

  f32x4 acc[8][4] = {};
  bf16x8 af[4][2], bfr[4][2];

  // prologue: stage tile0 + tile1 fully (16 loads/thread); drain tile0.
  STG_A(0, 0, 0); STG_B(0, 0, 0); STG_B(0, 1, 0); STG_A(0, 1, 0);
  STG_A(1, 0, 1); STG_B(1, 0, 1); STG_B(1, 1, 1); STG_A(1, 1, 1);
  VMC8; SBAR;

  for (int t = 0; t < niter; ++t) {
    const int c = t << 1;
    // ph1: RD A-h0 + B n0-1 (buf0); MFMA m0-3 x n0-1
    RD_A(0, 0, 0); RD_A(0, 0, 1); RD_A(0, 1, 0); RD_A(0, 1, 1);
    RD_A(0, 2, 0); RD_A(0, 2, 1); RD_A(0, 3, 0); RD_A(0, 3, 1);
    RD_B(0, 0, 0); RD_B(0, 0, 1); RD_B(0, 1, 0); RD_B(0, 1, 1);
    SCHED0;
    MFMA_PH(0, 0);
    SBAR;
    // ph2: RD B n2-3; STG A0(c+2), B0(c+2); MFMA m0-3 x n2-3
    RD_B(0, 2, 0); RD_B(0, 2, 1); RD_B(0, 3, 0); RD_B(0, 3, 1);
    STG_A(0, 0, c + 2); STG_B(0, 0, c + 2);
    SCHED0;
    MFMA_PH(0, 2);
    SBAR;
    // ph3: RD A-h1; STG B1(c+2); MFMA m4-7 x n0-1
    RD_A(0, 4, 0); RD_A(0, 4, 1); RD_A(0, 5, 0); RD_A(0, 5, 1);
    RD_A(0, 6, 0); RD_A(0, 6, 1); RD_A(0, 7, 0); RD_A(0, 7, 1);
    STG_B(0, 1, c + 2);
    SCHED0;
    MFMA_PH(4, 0);
    SBAR;
    // ph4: STG A1(c+2); MFMA m4-7 x n2-3; drain prev buf1 groups
    STG_A(0, 1, c + 2);
    SCHED0;
    MFMA_PH(4, 2);
    VMC8;
    SBAR;
    // ph5: RD A-h0 + B n0-1 (buf1); MFMA m0-3 x n0-1
    RD_A(1, 0, 0); RD_A(1, 0, 1); RD_A(1, 1, 0); RD_A(1, 1, 1);
    RD_A(1, 2, 0); RD_A(1, 2, 1); RD_A(1, 3, 0); RD_A(1, 3, 1);
    RD_B(1, 0, 0); RD_B(1, 0, 1); RD_B(1, 1, 0); RD_B(1, 1, 1);
    SCHED0;
    MFMA_PH(0, 0);
    SBAR;
    // ph6: RD B n2-3; STG A0(c+3), B0(c+3); MFMA m0-3 x n2-3
    RD_B(1, 2, 0); RD_B(1, 2, 1); RD_B(1, 3, 0); RD_B(1, 3, 1);
    STG_A(1, 0, c + 3); STG_B(1, 0, c + 3);
    SCHED0;
    MFMA_PH(0, 2);
    SBAR;
    // ph7: RD A-h1; STG B1(c+3); MFMA m4-7 x n0-1
    RD_A(1, 4, 0); RD_A(1, 4, 1); RD_A(1, 5, 0); RD_A(1, 5, 1);
    RD_A(1, 6, 0); RD_A(1, 6, 1); RD_A(1, 7, 0); RD_A(1, 7, 1);
    STG_B(1, 1, c + 3);
    SCHED0;
    MFMA_PH(4, 0);
    SBAR;
    // ph8: STG A1(c+3); MFMA m4-7 x n2-3; drain this-iter buf0 groups
    STG_A(1, 1, c + 3);
    SCHED0;
    MFMA_PH(4, 2);
    VMC8;
    SBAR;
  }

  // drain pending LDS-DMA before teardown/stores
  asm volatile("s_waitcnt vmcnt(0)" ::: "memory");

  float bv[4];
#pragma unroll
  for (int nf = 0; nf < 4; ++nf) bv[nf] = bias[n0 + wni * 64 + nf * 16 + l16];

  // C/D layout: col = lane&15, row = quad*4 + reg (m89-verified)
#pragma unroll
  for (int mi = 0; mi < 8; ++mi) {
    const long row0 = (long)(qbase + wmi * 128 + mi * 16 + quad * 4);
#pragma unroll
    for (int nf = 0; nf < 4; ++nf) {
      const int col = n0 + wni * 64 + nf * 16 + l16;
#pragma unroll
      for (int r = 0; r < 4; ++r) {
        float v = acc[mi][nf][r] + bv[nf];
        if (RELU_BF16) {
          v = fmaxf(v, 0.0f);
          ((bf16_t*)Cout)[(row0 + r) * N + col] = (bf16_t)v;
        } else {
          ((float*)Cout)[(row0 + r) * N + col] = v;
        }
      }
    }
  }
#undef ADST
#undef BDST
#undef STG_A
#undef STG_B
#undef RD_A
#undef RD_B
#undef MFMA_PH
#undef SCHED0
#undef SBAR
#undef VMC8
}

// ---------------------------------------------------------------- epilogue
__global__ __launch_bounds__(256) void epilogue_kernel(
    const float* __restrict__ z,                       // [NPAD][512]
    const float* __restrict__ Wc0, const float* __restrict__ bc0,
    const float* __restrict__ Wc1, const float* __restrict__ bc1,
    const unsigned* __restrict__ perm, const int* __restrict__ cnt,
    float* __restrict__ out_z, float* __restrict__ out_logits) {
  __shared__ float WcL[2][PROJ * 3];
  for (int i = threadIdx.x; i < PROJ * 3; i += 256) {
    WcL[0][i] = Wc0[i];
    WcL[1][i] = Wc1[i];
  }
  __syncthreads();
  const int wave = threadIdx.x >> 6;
  const int lane = threadIdx.x & 63;
  const int q = blockIdx.x * 4 + wave;
  const unsigned orig = perm[q];
  if (orig == SENT) return;             // pad row
  const int n_nat = cnt[0];
  const int off_oth = ((n_nat + 255) >> 8) << 8;
  const int g = (q < off_oth) ? 0 : 1;

  float zv[8];
  float ss = 0.f, l0 = 0.f, l1 = 0.f, l2 = 0.f;
#pragma unroll
  for (int i = 0; i < 8; ++i) {
    const int k = i * 64 + lane;
    float v = z[(long)q * PROJ + k];
    zv[i] = v;
    ss += v * v;
    float r = fmaxf(v, 0.f);
    const float* w = &WcL[g][k * 3];
    l0 += r * w[0];
    l1 += r * w[1];
    l2 += r * w[2];
  }
#pragma unroll
  for (int off = 32; off > 0; off >>= 1) {
    ss += __shfl_xor(ss, off);
    l0 += __shfl_xor(l0, off);
    l1 += __shfl_xor(l1, off);
    l2 += __shfl_xor(l2, off);
  }
  const float inv = 1.f / fmaxf(sqrtf(ss), 1e-12f);
#pragma unroll
  for (int i = 0; i < 8; ++i)
    out_z[(long)orig * PROJ + i * 64 + lane] = zv[i] * inv;
  if (lane == 0) {
    const float* bc = g ? bc1 : bc0;
    out_logits[(long)orig * 3 + 0] = l0 + bc[0];
    out_logits[(long)orig * 3 + 1] = l1 + bc[1];
    out_logits[(long)orig * 3 + 2] = l2 + bc[2];
  }
}

// ---------------------------------------------------------------- launch
extern "C" void kernel_launch(void* const* d_in, const int* in_sizes, int n_in,
                              void* d_out, int out_size, void* d_ws, size_t ws_size,
                              hipStream_t stream) {
  const float* x   = (const float*)d_in[0];
  const float* W1n = (const float*)d_in[1];
  const float* b1n = (const float*)d_in[2];
  const float* W2n = (const float*)d_in[3];
  const float* b2n = (const float*)d_in[4];
  const float* Wcn = (const float*)d_in[5];
  const float* bcn = (const float*)d_in[6];
  const float* W1o = (const float*)d_in[7];
  const float* b1o = (const float*)d_in[8];
  const float* W2o = (const float*)d_in[9];
  const float* b2o = (const float*)d_in[10];
  const float* Wco = (const float*)d_in[11];
  const float* bco = (const float*)d_in[12];

  char* ws = (char*)d_ws;
  bf16_t* xbf  = (bf16_t*)ws;                                   // 268,435,456
  float*  z_ws = (float*)ws;                                    // alias (xbf dead after GEMM1)
  size_t off = 268435456;
  bf16_t* W1tn = (bf16_t*)(ws + off); off += (size_t)FEAT * HID * 2;
  bf16_t* W1to = (bf16_t*)(ws + off); off += (size_t)FEAT * HID * 2;
  bf16_t* W2tn = (bf16_t*)(ws + off); off += (size_t)HID * PROJ * 2;
  bf16_t* W2to = (bf16_t*)(ws + off); off += (size_t)HID * PROJ * 2;
  bf16_t* h_ws = (bf16_t*)(ws + off); off += (size_t)NPAD * HID * 2;
  unsigned* perm = (unsigned*)(ws + off); off += (size_t)NPAD * 4;
  int* cnt = (int*)(ws + off);

  float* out_z = (float*)d_out;
  float* out_logits = out_z + (size_t)NROWS * PROJ;

  static bool attr_done = false;
  if (!attr_done) {
    auto* k1 = gemm256_kernel<true, true>;
    auto* k2 = gemm256_kernel<false, false>;
    (void)hipFuncSetAttribute(reinterpret_cast<const void*>(k1),
                              hipFuncAttributeMaxDynamicSharedMemorySize, 131072);
    (void)hipFuncSetAttribute(reinterpret_cast<const void*>(k2),
                              hipFuncAttributeMaxDynamicSharedMemorySize, 131072);
    attr_done = true;
  }

  // 1) partition rows by flag (padded to 256, sentinel-filled perm)
  init_kernel<<<(NPAD + 255) / 256, 256, 0, stream>>>(perm, cnt);
  count_kernel<<<NROWS / 256, 256, 0, stream>>>(x, cnt);
  scatter_kernel<<<NROWS / 256, 256, 0, stream>>>(x, perm, cnt);

  // 2) dtype conversions
  convert_x_kernel<<<2048, 256, 0, stream>>>(x, xbf);
  transpose_convert_kernel<<<dim3(HID / 32, FEAT / 32), 256, 0, stream>>>(W1n, W1tn, FEAT, HID);
  transpose_convert_kernel<<<dim3(HID / 32, FEAT / 32), 256, 0, stream>>>(W1o, W1to, FEAT, HID);
  transpose_convert_kernel<<<dim3(PROJ / 32, HID / 32), 256, 0, stream>>>(W2n, W2tn, HID, PROJ);
  transpose_convert_kernel<<<dim3(PROJ / 32, HID / 32), 256, 0, stream>>>(W2o, W2to, HID, PROJ);

  // 3) h = relu(feat @ W1 + b1)  (gathered A rows, bf16 out)
  gemm256_kernel<true, true><<<dim3(MT256 * 8), 512, 131072, stream>>>(
      xbf, W1tn, W1to, b1n, b1o, (void*)h_ws, perm, cnt, FEAT, HID, 8);

  // 4) z = h @ W2 + b2  (fp32 out, overwrites dead xbf region)
  gemm256_kernel<false, false><<<dim3(MT256 * 2), 512, 131072, stream>>>(
      h_ws, W2tn, W2to, b2n, b2o, (void*)z_ws, perm, cnt, HID, PROJ, 2);

  // 5) normalize + classifier, scatter to original row order
  epilogue_kernel<<<NPAD / 4, 256, 0, stream>>>(
      z_ws, Wcn, bcn, Wco, bco, perm, cnt, out_z, out_logits);
}